// Round 6
// baseline (240.208 us; speedup 1.0000x reference)
//
#include <hip/hip_runtime.h>
#include <hip/hip_bf16.h>

// ActorNetwork fused pipeline for MI355X — round 6.
// k_gat v5: nb held in registers (32 VGPR), shfl reduces, ~12 KB LDS, no LDS staging.
// All other kernels byte-identical to round 5.

typedef unsigned short u16;
typedef unsigned int   u32;
typedef __attribute__((ext_vector_type(8))) short bf16x8;
typedef __attribute__((ext_vector_type(4))) float f32x4;

#define KFUSE  672   // 641 padded to 21*32
#define ACT_TOT (8192*16)

__device__ __forceinline__ u16 f2bf(float x){
  u32 u = __float_as_uint(x);
  u += 0x7fffu + ((u >> 16) & 1u);   // round-to-nearest-even
  return (u16)(u >> 16);
}
__device__ __forceinline__ float bf2f(u16 h){ return __uint_as_float(((u32)h) << 16); }

// generic: one MFMA B-fragment (64 lanes) from fp32 src
__device__ __forceinline__ void frag_one(const float* __restrict__ src, int ld, int col0,
                                         int NT, u16* __restrict__ dhi, u16* __restrict__ dlo,
                                         int f, int fsrc, int l){
  int kt = fsrc / NT, nt = fsrc % NT;
  int kbase = kt*32 + (l >> 4)*8, n = col0 + nt*16 + (l & 15);
  size_t o = ((size_t)f*64 + l)*8;
  #pragma unroll
  for(int i = 0; i < 8; ++i){
    float w = src[(size_t)(kbase + i)*ld + n];
    u16 h = f2bf(w);
    dhi[o + i] = h;
    dlo[o + i] = f2bf(w - bf2f(h));
  }
}

// ---------- prep kernel 1: probe + wa + wbig + direct weight frags + h split ----------
#define B_WBIG0 1
#define B_WRZA  673
#define B_WRZB  737
#define B_WIN   801
#define B_WHN   833
#define B_F1    865
#define B_F2    897
#define B_SPLIT 913
// grid = 1937
__global__ __launch_bounds__(256) void k_prep1(
    const unsigned char* __restrict__ maskb, int* __restrict__ flag,
    const float* __restrict__ Wg, const float* __restrict__ ag,
    float* __restrict__ was, float* __restrict__ wad,
    const float* __restrict__ fW, float* __restrict__ wbig,
    const float* __restrict__ Wih, const float* __restrict__ Whh,
    const float* __restrict__ W1, const float* __restrict__ W2,
    u16* __restrict__ wrzh, u16* __restrict__ wrzl,
    u16* __restrict__ winh, u16* __restrict__ winl,
    u16* __restrict__ whnh, u16* __restrict__ whnl,
    u16* __restrict__ f1h, u16* __restrict__ f1l,
    u16* __restrict__ f2h, u16* __restrict__ f2l,
    const float* __restrict__ hidden, u16* __restrict__ acath, u16* __restrict__ acatl)
{
  int bx = blockIdx.x, t = threadIdx.x;
  if(bx == 0){
    if(t == 0){
      int s = 0;
      for(int i = 1; i < 256; i += 4) s += maskb[i];
      *flag = (s == 0) ? 1 : 0;
    }
    #pragma unroll
    for(int v = 0; v < 2; ++v){
      int idx = v*256 + t, k = idx & 127, h = idx >> 7;
      float s = 0.f, d = 0.f;
      for(int f = 0; f < 64; ++f){
        float w = Wg[k*256 + h*64 + f];
        s += w * ag[h*128 + f];
        d += w * ag[h*128 + 64 + f];
      }
      was[k*4 + h] = s; wad[k*4 + h] = d;
    }
  } else if(bx < B_WRZA){
    int r = bx - B_WBIG0, j = t;
    float v;
    if(r < 129) v = fW[r*256 + j];
    else if(r < 641){
      int h = (r - 129) >> 7, kk = (r - 129) & 127;
      float s = 0.f;
      for(int f = 0; f < 64; ++f) s += Wg[kk*256 + h*64 + f] * fW[(129 + h*64 + f)*256 + j];
      v = s;
    } else v = 0.f;
    wbig[r*256 + j] = v;
  } else if(bx < B_SPLIT){
    int sub = t >> 6, l = t & 63;
    if(bx < B_WRZB){        // Wih rz: frags 0..255, NT=32
      int f = (bx - B_WRZA)*4 + sub;
      frag_one(Wih, 768, 0, 32, wrzh, wrzl, f, f, l);
    } else if(bx < B_WIN){  // Whh rz: frags 256..511 (src frag 0..255)
      int fl = (bx - B_WRZB)*4 + sub;
      frag_one(Whh, 768, 0, 32, wrzh, wrzl, 256 + fl, fl, l);
    } else if(bx < B_WHN){  // Wih n: 128 frags NT=16 col0 512
      int f = (bx - B_WIN)*4 + sub;
      frag_one(Wih, 768, 512, 16, winh, winl, f, f, l);
    } else if(bx < B_F1){   // Whh n
      int f = (bx - B_WHN)*4 + sub;
      frag_one(Whh, 768, 512, 16, whnh, whnl, f, f, l);
    } else if(bx < B_F2){   // W1: 128 frags NT=16
      int f = (bx - B_F1)*4 + sub;
      frag_one(W1, 256, 0, 16, f1h, f1l, f, f, l);
    } else {                // W2: 64 frags NT=8
      int f = (bx - B_F2)*4 + sub;
      frag_one(W2, 128, 0, 8, f2h, f2l, f, f, l);
    }
  } else {
    // h split -> ACAT cols 256..511 (row stride 512)
    int i = (bx - B_SPLIT)*256 + t;     // 0..262143, 8 f32 each
    int idx8 = i*8, row = idx8 >> 8, col = idx8 & 255;
    const float4* p = (const float4*)(hidden + (size_t)idx8);
    float4 v0 = p[0], v1 = p[1];
    float vv[8] = {v0.x,v0.y,v0.z,v0.w,v1.x,v1.y,v1.z,v1.w};
    u16 h8[8], l8[8];
    #pragma unroll
    for(int q = 0; q < 8; ++q){ u16 h = f2bf(vv[q]); h8[q] = h; l8[q] = f2bf(vv[q] - bf2f(h)); }
    uint4 uh = { (u32)h8[0] | ((u32)h8[1]<<16), (u32)h8[2] | ((u32)h8[3]<<16),
                 (u32)h8[4] | ((u32)h8[5]<<16), (u32)h8[6] | ((u32)h8[7]<<16) };
    uint4 ul = { (u32)l8[0] | ((u32)l8[1]<<16), (u32)l8[2] | ((u32)l8[3]<<16),
                 (u32)l8[4] | ((u32)l8[5]<<16), (u32)l8[6] | ((u32)l8[7]<<16) };
    size_t off = (size_t)row*512 + 256 + col;
    *(uint4*)(acath + off) = uh;
    *(uint4*)(acatl + off) = ul;
  }
}

// ---------- prep kernel 2: wbig frags (depends on prep1) ----------
__global__ __launch_bounds__(256) void k_prep2(
    const float* __restrict__ wbig, u16* __restrict__ ffh, u16* __restrict__ ffl)
{
  int f = blockIdx.x*4 + (threadIdx.x >> 6), l = threadIdx.x & 63;   // 84 blocks -> 336 frags
  frag_one(wbig, 256, 0, 16, ffh, ffl, f, f, l);
}

// ---------- GAT kernel v5: register-resident nb, shfl reduces, ~12 KB LDS ----------
// thread t: ch = t&31 (k-chunk, k = ch*4..ch*4+3), r = t>>5; iter q -> row n = q*8+r
__global__ __launch_bounds__(256) void k_gat(
    const float* __restrict__ nbg, const float* __restrict__ node,
    const void* __restrict__ maskp, const int* __restrict__ flagp,
    const float* __restrict__ was, const float* __restrict__ wad,
    u16* __restrict__ xhi, u16* __restrict__ xlo)
{
  __shared__ float s_ed[64*4];      // [n][h]
  __shared__ float s_es[4];
  __shared__ float s_alpha[64*4];   // [n][h]
  __shared__ float s_red[4*32*20];  // [wv][ch][20] (pad 16->20 words vs bank stride)
  int b = blockIdx.x, t = threadIdx.x;
  int ch = t & 31, r = t >> 5;
  int lane = t & 63, wv = t >> 6;
  const float* nb = nbg + (size_t)b*8192;
  const int isint = *flagp;

  // wad rows ch*4..ch*4+3 in regs (coalesced: lane ch reads 64B at ch*64)
  float4 wd0 = *(const float4*)(wad + (ch*4+0)*4);
  float4 wd1 = *(const float4*)(wad + (ch*4+1)*4);
  float4 wd2 = *(const float4*)(wad + (ch*4+2)*4);
  float4 wd3 = *(const float4*)(wad + (ch*4+3)*4);

  // coalesced load of 8 chunks into registers (rows q*8+r, fixed k-span)
  float4 cdat[8];
  #pragma unroll
  for(int q = 0; q < 8; ++q)
    cdat[q] = *(const float4*)(nb + (size_t)(q*256 + t)*4);

  // enc part of x_cat: [sin, cos, node_obs[1:128]] + zero pad 641..671
  if(t < 129){
    float v;
    if(t < 2){
      float ph = node[(size_t)b*128] * (6.2831853071795864769f / 24.0f);
      v = (t == 0) ? sinf(ph) : cosf(ph);
    } else v = node[(size_t)b*128 + (t-1)];
    u16 h = f2bf(v);
    size_t o = (size_t)b*KFUSE + t;
    xhi[o] = h; xlo[o] = f2bf(v - bf2f(h));
  } else if(t < 160){
    size_t o = (size_t)b*KFUSE + 641 + (t - 129);
    xhi[o] = 0; xlo[o] = 0;
  }

  // pass 1: ed[n][h] per q via 16 FMA + half-wave (32-lane) shfl reduce
  #pragma unroll
  for(int q = 0; q < 8; ++q){
    float4 v = cdat[q];
    float e0 = v.x*wd0.x + v.y*wd1.x + v.z*wd2.x + v.w*wd3.x;
    float e1 = v.x*wd0.y + v.y*wd1.y + v.z*wd2.y + v.w*wd3.y;
    float e2 = v.x*wd0.z + v.y*wd1.z + v.z*wd2.z + v.w*wd3.z;
    float e3 = v.x*wd0.w + v.y*wd1.w + v.z*wd2.w + v.w*wd3.w;
    #pragma unroll
    for(int off = 16; off; off >>= 1){
      e0 += __shfl_xor(e0, off);
      e1 += __shfl_xor(e1, off);
      e2 += __shfl_xor(e2, off);
      e3 += __shfl_xor(e3, off);
    }
    if(ch == 0){
      int n = q*8 + r;
      *(float4*)(s_ed + n*4) = (float4){e0, e1, e2, e3};
    }
  }

  // es[h] from row 0 (chunks live in lanes 0..31 of wave 0, q=0); full-wave reduce w/ mask
  if(wv == 0){
    float4 w0 = *(const float4*)(was + (ch*4+0)*4);
    float4 w1 = *(const float4*)(was + (ch*4+1)*4);
    float4 w2 = *(const float4*)(was + (ch*4+2)*4);
    float4 w3 = *(const float4*)(was + (ch*4+3)*4);
    float m = (lane < 32) ? 1.f : 0.f;
    float4 v = cdat[0];
    float s0 = m*(v.x*w0.x + v.y*w1.x + v.z*w2.x + v.w*w3.x);
    float s1 = m*(v.x*w0.y + v.y*w1.y + v.z*w2.y + v.w*w3.y);
    float s2 = m*(v.x*w0.z + v.y*w1.z + v.z*w2.z + v.w*w3.z);
    float s3 = m*(v.x*w0.w + v.y*w1.w + v.z*w2.w + v.w*w3.w);
    #pragma unroll
    for(int off = 32; off; off >>= 1){
      s0 += __shfl_xor(s0, off);
      s1 += __shfl_xor(s1, off);
      s2 += __shfl_xor(s2, off);
      s3 += __shfl_xor(s3, off);
    }
    if(lane == 0){ s_es[0]=s0; s_es[1]=s1; s_es[2]=s2; s_es[3]=s3; }
  }
  __syncthreads();

  // softmax: wave = head h2, lane = neighbor n2
  {
    int n2 = lane, h2 = wv;
    float e = s_es[h2] + s_ed[n2*4 + h2];
    e = (e > 0.f) ? e : 0.2f*e;
    bool valid;
    if(isint) valid = ((const u32*)maskp)[(size_t)b*64 + n2] != 0u;
    else      valid = ((const unsigned char*)maskp)[(size_t)b*64 + n2] != 0;
    float ev = valid ? e : -1e30f;
    float mx = ev;
    for(int off = 32; off; off >>= 1) mx = fmaxf(mx, __shfl_xor(mx, off));
    float p = valid ? expf(ev - mx) : 0.f;
    float s = p;
    for(int off = 32; off; off >>= 1) s += __shfl_xor(s, off);
    s_alpha[n2*4 + h2] = p / s;   // [n][h]
  }
  __syncthreads();

  // pass 2: pa[h][i] += alpha[n][h] * chunk[q][i] (nb from registers!)
  float pa[4][4];
  #pragma unroll
  for(int h = 0; h < 4; ++h)
    #pragma unroll
    for(int i = 0; i < 4; ++i) pa[h][i] = 0.f;
  #pragma unroll
  for(int q = 0; q < 8; ++q){
    int n = q*8 + r;
    float4 al = *(const float4*)(s_alpha + n*4);   // broadcast within half-wave
    float4 v = cdat[q];
    pa[0][0] += al.x*v.x; pa[0][1] += al.x*v.y; pa[0][2] += al.x*v.z; pa[0][3] += al.x*v.w;
    pa[1][0] += al.y*v.x; pa[1][1] += al.y*v.y; pa[1][2] += al.y*v.z; pa[1][3] += al.y*v.w;
    pa[2][0] += al.z*v.x; pa[2][1] += al.z*v.y; pa[2][2] += al.z*v.z; pa[2][3] += al.z*v.w;
    pa[3][0] += al.w*v.x; pa[3][1] += al.w*v.y; pa[3][2] += al.w*v.z; pa[3][3] += al.w*v.w;
  }
  // reduce r and r^1 (lanes t, t^32 share ch within a wave)
  #pragma unroll
  for(int h = 0; h < 4; ++h)
    #pragma unroll
    for(int i = 0; i < 4; ++i) pa[h][i] += __shfl_xor(pa[h][i], 32);
  if(lane < 32){
    #pragma unroll
    for(int h = 0; h < 4; ++h)
      *(float4*)(s_red + (wv*32 + ch)*20 + h*4) = (float4){pa[h][0], pa[h][1], pa[h][2], pa[h][3]};
  }
  __syncthreads();
  // final reduce over waves + hi/lo write: thread (h = t>>5, c2 = t&31) -> 4 k-values
  if(t < 128){
    int h = t >> 5, c2 = t & 31;
    float4 acc = {0.f, 0.f, 0.f, 0.f};
    #pragma unroll
    for(int w2 = 0; w2 < 4; ++w2){
      float4 p = *(const float4*)(s_red + (w2*32 + c2)*20 + h*4);
      acc.x += p.x; acc.y += p.y; acc.z += p.z; acc.w += p.w;
    }
    float vv[4] = {acc.x, acc.y, acc.z, acc.w};
    size_t o = (size_t)b*KFUSE + 129 + h*128 + c2*4;
    #pragma unroll
    for(int i = 0; i < 4; ++i){
      u16 hh = f2bf(vv[i]);
      xhi[o+i] = hh; xlo[o+i] = f2bf(vv[i] - bf2f(hh));
    }
  }
}

// ---------- split-bf16 MFMA GEMM: ROWF row-frags, col-split grid ----------
template<int KT, int NT_TOT, int NPW, int ROWF>
__global__ __launch_bounds__(256) void k_gemm3(
    const u16* __restrict__ xhi, const u16* __restrict__ xlo, int lda,
    const u16* __restrict__ wfhi, const u16* __restrict__ wflo,
    const float* __restrict__ bias,
    u16* __restrict__ ohi, u16* __restrict__ olo, int ost, int ocol)
{
  int l = threadIdx.x & 63, w = threadIdx.x >> 6;
  int m0 = blockIdx.x * (16*ROWF);
  int ntbase = blockIdx.y * (4*NPW) + w*NPW;
  f32x4 acc[NPW][ROWF];
  #pragma unroll
  for(int j = 0; j < NPW; ++j)
    #pragma unroll
    for(int rf = 0; rf < ROWF; ++rf) acc[j][rf] = (f32x4){0.f,0.f,0.f,0.f};
  size_t arow[ROWF];
  #pragma unroll
  for(int rf = 0; rf < ROWF; ++rf)
    arow[rf] = (size_t)(m0 + rf*16 + (l & 15))*lda + (size_t)((l >> 4)*8);
  for(int kt = 0; kt < KT; ++kt){
    bf16x8 ah[ROWF], al[ROWF];
    #pragma unroll
    for(int rf = 0; rf < ROWF; ++rf){
      ah[rf] = *(const bf16x8*)(xhi + arow[rf] + kt*32);
      al[rf] = *(const bf16x8*)(xlo + arow[rf] + kt*32);
    }
    #pragma unroll
    for(int j = 0; j < NPW; ++j){
      size_t bo = ((size_t)(kt*NT_TOT + ntbase + j)*64 + l)*8;
      bf16x8 bh = *(const bf16x8*)(wfhi + bo);
      bf16x8 bl = *(const bf16x8*)(wflo + bo);
      #pragma unroll
      for(int rf = 0; rf < ROWF; ++rf){
        acc[j][rf] = __builtin_amdgcn_mfma_f32_16x16x32_bf16(ah[rf], bh, acc[j][rf], 0, 0, 0);
        acc[j][rf] = __builtin_amdgcn_mfma_f32_16x16x32_bf16(ah[rf], bl, acc[j][rf], 0, 0, 0);
        acc[j][rf] = __builtin_amdgcn_mfma_f32_16x16x32_bf16(al[rf], bh, acc[j][rf], 0, 0, 0);
      }
    }
  }
  #pragma unroll
  for(int j = 0; j < NPW; ++j){
    int col = (ntbase + j)*16 + (l & 15);
    float bv = bias[col];
    #pragma unroll
    for(int rf = 0; rf < ROWF; ++rf){
      int r0 = m0 + rf*16 + (l >> 4)*4;
      #pragma unroll
      for(int q = 0; q < 4; ++q){
        float y = fmaxf(acc[j][rf][q] + bv, 0.f);
        size_t o = (size_t)(r0 + q)*ost + ocol + col;
        u16 h = f2bf(y);
        ohi[o] = h; olo[o] = f2bf(y - bf2f(h));
      }
    }
  }
}

// ---------- fused GRU v2: 512 threads, 32 rows/block, 8 waves x 32 cols ----------
__global__ __launch_bounds__(512) void k_gru(
    const u16* __restrict__ ah_, const u16* __restrict__ al_,
    const u16* __restrict__ wrzh, const u16* __restrict__ wrzl,
    const u16* __restrict__ winh, const u16* __restrict__ winl,
    const u16* __restrict__ whnh, const u16* __restrict__ whnl,
    const float* __restrict__ bih, const float* __restrict__ bhh,
    const float* __restrict__ hidden, const float* __restrict__ lng,
    const float* __restrict__ lnb,
    float* __restrict__ hout, u16* __restrict__ belh, u16* __restrict__ bell)
{
  __shared__ float s_s1[256], s_s2[256];
  __shared__ float s_mu[32], s_rs[32];
  int l = threadIdx.x & 63, w = threadIdx.x >> 6;   // 8 waves
  int m0 = blockIdx.x*32;
  f32x4 ar[2][2], az[2][2], aa[2][2], ab[2][2];
  #pragma unroll
  for(int j = 0; j < 2; ++j)
    #pragma unroll
    for(int rf = 0; rf < 2; ++rf){
      ar[j][rf] = (f32x4){0.f,0.f,0.f,0.f}; az[j][rf] = (f32x4){0.f,0.f,0.f,0.f};
      aa[j][rf] = (f32x4){0.f,0.f,0.f,0.f}; ab[j][rf] = (f32x4){0.f,0.f,0.f,0.f};
    }
  size_t arow[2];
  #pragma unroll
  for(int rf = 0; rf < 2; ++rf)
    arow[rf] = (size_t)(m0 + rf*16 + (l & 15))*512 + (size_t)((l >> 4)*8);
  for(int kt = 0; kt < 16; ++kt){
    bf16x8 ah[2], al[2];
    #pragma unroll
    for(int rf = 0; rf < 2; ++rf){
      ah[rf] = *(const bf16x8*)(ah_ + arow[rf] + kt*32);
      al[rf] = *(const bf16x8*)(al_ + arow[rf] + kt*32);
    }
    #pragma unroll
    for(int j = 0; j < 2; ++j){
      int nt = w*2 + j;
      int fr = kt*32 + nt;
      size_t bo = ((size_t)fr*64 + l)*8;
      bf16x8 bh = *(const bf16x8*)(wrzh + bo);
      bf16x8 bl = *(const bf16x8*)(wrzl + bo);
      size_t bo2 = bo + (size_t)16*64*8;    // z-frags at nt+16
      bf16x8 bh2 = *(const bf16x8*)(wrzh + bo2);
      bf16x8 bl2 = *(const bf16x8*)(wrzl + bo2);
      #pragma unroll
      for(int rf = 0; rf < 2; ++rf){
        ar[j][rf] = __builtin_amdgcn_mfma_f32_16x16x32_bf16(ah[rf], bh, ar[j][rf], 0, 0, 0);
        ar[j][rf] = __builtin_amdgcn_mfma_f32_16x16x32_bf16(ah[rf], bl, ar[j][rf], 0, 0, 0);
        ar[j][rf] = __builtin_amdgcn_mfma_f32_16x16x32_bf16(al[rf], bh, ar[j][rf], 0, 0, 0);
        az[j][rf] = __builtin_amdgcn_mfma_f32_16x16x32_bf16(ah[rf], bh2, az[j][rf], 0, 0, 0);
        az[j][rf] = __builtin_amdgcn_mfma_f32_16x16x32_bf16(ah[rf], bl2, az[j][rf], 0, 0, 0);
        az[j][rf] = __builtin_amdgcn_mfma_f32_16x16x32_bf16(al[rf], bh2, az[j][rf], 0, 0, 0);
      }
    }
  }
  for(int kt = 0; kt < 8; ++kt){
    bf16x8 fh[2], fl2[2], gh[2], gl[2];
    #pragma unroll
    for(int rf = 0; rf < 2; ++rf){
      fh[rf]  = *(const bf16x8*)(ah_ + arow[rf] + kt*32);
      fl2[rf] = *(const bf16x8*)(al_ + arow[rf] + kt*32);
      gh[rf]  = *(const bf16x8*)(ah_ + arow[rf] + 256 + kt*32);
      gl[rf]  = *(const bf16x8*)(al_ + arow[rf] + 256 + kt*32);
    }
    #pragma unroll
    for(int j = 0; j < 2; ++j){
      int nt = w*2 + j;
      size_t bo = ((size_t)(kt*16 + nt)*64 + l)*8;
      bf16x8 bh = *(const bf16x8*)(winh + bo);
      bf16x8 bl = *(const bf16x8*)(winl + bo);
      bf16x8 ch = *(const bf16x8*)(whnh + bo);
      bf16x8 cl2 = *(const bf16x8*)(whnl + bo);
      #pragma unroll
      for(int rf = 0; rf < 2; ++rf){
        aa[j][rf] = __builtin_amdgcn_mfma_f32_16x16x32_bf16(fh[rf], bh, aa[j][rf], 0, 0, 0);
        aa[j][rf] = __builtin_amdgcn_mfma_f32_16x16x32_bf16(fh[rf], bl, aa[j][rf], 0, 0, 0);
        aa[j][rf] = __builtin_amdgcn_mfma_f32_16x16x32_bf16(fl2[rf], bh, aa[j][rf], 0, 0, 0);
        ab[j][rf] = __builtin_amdgcn_mfma_f32_16x16x32_bf16(gh[rf], ch, ab[j][rf], 0, 0, 0);
        ab[j][rf] = __builtin_amdgcn_mfma_f32_16x16x32_bf16(gh[rf], cl2, ab[j][rf], 0, 0, 0);
        ab[j][rf] = __builtin_amdgcn_mfma_f32_16x16x32_bf16(gl[rf], ch, ab[j][rf], 0, 0, 0);
      }
    }
  }
  int cl = l & 15, rq = l >> 4;
  float hnew[2][2][4];
  float s1p[2][4], s2p[2][4];
  #pragma unroll
  for(int rf = 0; rf < 2; ++rf)
    #pragma unroll
    for(int q = 0; q < 4; ++q){ s1p[rf][q] = 0.f; s2p[rf][q] = 0.f; }
  #pragma unroll
  for(int j = 0; j < 2; ++j){
    int col = w*32 + j*16 + cl;
    float br = bih[col] + bhh[col];
    float bz = bih[256+col] + bhh[256+col];
    float bi = bih[512+col];
    float bh2 = bhh[512+col];
    #pragma unroll
    for(int rf = 0; rf < 2; ++rf){
      #pragma unroll
      for(int q = 0; q < 4; ++q){
        int row = m0 + rf*16 + rq*4 + q;
        float rs = ar[j][rf][q] + br;
        float zs = az[j][rf][q] + bz;
        float in_ = aa[j][rf][q] + bi;
        float hn  = ab[j][rf][q] + bh2;
        float h   = hidden[(size_t)row*256 + col];
        float r = 1.f/(1.f + expf(-rs));
        float z = 1.f/(1.f + expf(-zs));
        float nv = tanhf(in_ + r*hn);
        float hv = (1.f - z)*nv + z*h;
        hnew[j][rf][q] = hv;
        hout[(size_t)row*256 + col] = hv;
        s1p[rf][q] += hv; s2p[rf][q] += hv*hv;
      }
    }
  }
  #pragma unroll
  for(int rf = 0; rf < 2; ++rf)
    #pragma unroll
    for(int q = 0; q < 4; ++q){
      float a = s1p[rf][q], b2 = s2p[rf][q];
      for(int off = 1; off < 16; off <<= 1){
        a += __shfl_xor(a, off); b2 += __shfl_xor(b2, off);
      }
      if(cl == 0){
        int rloc = rf*16 + rq*4 + q;
        s_s1[w*32 + rloc] = a; s_s2[w*32 + rloc] = b2;
      }
    }
  __syncthreads();
  if(threadIdx.x < 32){
    int rloc = threadIdx.x;
    float t1 = 0.f, t2 = 0.f;
    #pragma unroll
    for(int ww = 0; ww < 8; ++ww){ t1 += s_s1[ww*32 + rloc]; t2 += s_s2[ww*32 + rloc]; }
    float mu = t1 * (1.f/256.f);
    float var = t2 * (1.f/256.f) - mu*mu;
    s_mu[rloc] = mu; s_rs[rloc] = rsqrtf(var + 1e-5f);
  }
  __syncthreads();
  #pragma unroll
  for(int j = 0; j < 2; ++j){
    int col = w*32 + j*16 + cl;
    float g = lng[col], bb = lnb[col];
    #pragma unroll
    for(int rf = 0; rf < 2; ++rf){
      #pragma unroll
      for(int q = 0; q < 4; ++q){
        int rloc = rf*16 + rq*4 + q;
        float bel = (hnew[j][rf][q] - s_mu[rloc]) * s_rs[rloc] * g + bb;
        u16 hb = f2bf(bel);
        size_t o = (size_t)(m0 + rloc)*256 + col;
        belh[o] = hb; bell[o] = f2bf(bel - bf2f(hb));
      }
    }
  }
}

// ---------- fused W2 GEMM + W3 head + project_power: 64 rows/block ----------
__global__ __launch_bounds__(256) void k_w2head(
    const u16* __restrict__ xhi, const u16* __restrict__ xlo,
    const u16* __restrict__ wfhi, const u16* __restrict__ wflo,
    const float* __restrict__ b2, const float* __restrict__ W3,
    const float* __restrict__ b3, float* __restrict__ act)
{
  __shared__ float sx2[64*128];
  __shared__ float sW3[2048];
  int t = threadIdx.x, l = t & 63, w = t >> 6;
  int m0 = blockIdx.x*64;
  for(int i = t; i < 2048; i += 256) sW3[i] = W3[i];
  f32x4 acc[2][4];
  #pragma unroll
  for(int j = 0; j < 2; ++j)
    #pragma unroll
    for(int rf = 0; rf < 4; ++rf) acc[j][rf] = (f32x4){0.f,0.f,0.f,0.f};
  size_t arow[4];
  #pragma unroll
  for(int rf = 0; rf < 4; ++rf)
    arow[rf] = (size_t)(m0 + rf*16 + (l & 15))*256 + (size_t)((l >> 4)*8);
  for(int kt = 0; kt < 8; ++kt){
    bf16x8 ah[4], al[4];
    #pragma unroll
    for(int rf = 0; rf < 4; ++rf){
      ah[rf] = *(const bf16x8*)(xhi + arow[rf] + kt*32);
      al[rf] = *(const bf16x8*)(xlo + arow[rf] + kt*32);
    }
    #pragma unroll
    for(int j = 0; j < 2; ++j){
      size_t bo = ((size_t)(kt*8 + w*2 + j)*64 + l)*8;
      bf16x8 bh = *(const bf16x8*)(wfhi + bo);
      bf16x8 bl = *(const bf16x8*)(wflo + bo);
      #pragma unroll
      for(int rf = 0; rf < 4; ++rf){
        acc[j][rf] = __builtin_amdgcn_mfma_f32_16x16x32_bf16(ah[rf], bh, acc[j][rf], 0, 0, 0);
        acc[j][rf] = __builtin_amdgcn_mfma_f32_16x16x32_bf16(ah[rf], bl, acc[j][rf], 0, 0, 0);
        acc[j][rf] = __builtin_amdgcn_mfma_f32_16x16x32_bf16(al[rf], bh, acc[j][rf], 0, 0, 0);
      }
    }
  }
  int cl = l & 15, rq = l >> 4;
  #pragma unroll
  for(int j = 0; j < 2; ++j){
    int col = (w*2 + j)*16 + cl;
    float bv = b2[col];
    #pragma unroll
    for(int rf = 0; rf < 4; ++rf){
      #pragma unroll
      for(int q = 0; q < 4; ++q){
        int rloc = rf*16 + rq*4 + q;
        sx2[rloc*128 + col] = fmaxf(acc[j][rf][q] + bv, 0.f);
      }
    }
  }
  __syncthreads();
  int j = t & 15, rl = t >> 4;
  #pragma unroll
  for(int rr = 0; rr < 4; ++rr){
    int rloc = rr*16 + rl;
    const float* xr = sx2 + rloc*128;
    float raw = b3[j];
    #pragma unroll 8
    for(int k4 = 0; k4 < 32; ++k4){
      float4 v = *(const float4*)(xr + k4*4);
      raw += v.x*sW3[(k4*4+0)*16 + j] + v.y*sW3[(k4*4+1)*16 + j]
           + v.z*sW3[(k4*4+2)*16 + j] + v.w*sW3[(k4*4+3)*16 + j];
    }
    float c0 = fminf(fmaxf(raw, 0.f), 0.5f);
    float tot = c0;
    for(int off = 8; off; off >>= 1) tot += __shfl_xor(tot, off);
    float mx = raw;
    for(int off = 8; off; off >>= 1) mx = fmaxf(mx, __shfl_xor(mx, off));
    bool feas = (tot <= 1.0f);
    float lo = 0.f, hi = fmaxf(mx, 0.f);
    for(int it = 0; it < 60; ++it){
      float mid = 0.5f*(lo + hi);
      float s = fminf(fmaxf(raw - mid, 0.f), 0.5f);
      for(int off = 8; off; off >>= 1) s += __shfl_xor(s, off);
      bool over = s > 1.0f;
      lo = over ? mid : lo;
      hi = over ? hi : mid;
    }
    float muv = feas ? 0.f : hi;
    act[(size_t)(m0 + rloc)*16 + j] = fminf(fmaxf(raw - muv, 0.f), 0.5f);
  }
}

// ---------- workspace layout (bytes) ----------
#define OFF_FLAG   0u
#define OFF_WAS    4096u
#define OFF_WAD    8192u
#define OFF_WBIG   12288u        // 672*256*4 = 688128
#define OFF_FFH    700416u       // 336 frags * 1024 = 344064
#define OFF_FFL    1044480u
#define OFF_WRZH   1388544u      // 512 frags * 1024 = 524288
#define OFF_WRZL   1912832u
#define OFF_WINH   2437120u      // 128 frags * 1024 = 131072
#define OFF_WINL   2568192u
#define OFF_WHNH   2699264u
#define OFF_WHNL   2830336u
#define OFF_F1H    2961408u      // 128 frags
#define OFF_F1L    3092480u
#define OFF_F2H    3223552u      // 64 frags * 1024 = 65536
#define OFF_F2L    3289088u
#define OFF_XCATH  3354624u      // 8192*672*2 = 11010048
#define OFF_XCATL  14364672u
#define OFF_ACATH  25374720u     // 8192*512*2 = 8388608
#define OFF_ACATL  33763328u
#define OFF_BELH   42151936u     // 8192*256*2 = 4194304
#define OFF_BELL   46346240u
#define OFF_X1H    50540544u
#define OFF_X1L    54734848u
// total: 58,929,152 bytes

extern "C" void kernel_launch(void* const* d_in, const int* in_sizes, int n_in,
                              void* d_out, int out_size, void* d_ws, size_t ws_size,
                              hipStream_t stream){
  const float* node   = (const float*)d_in[0];
  const float* nbr    = (const float*)d_in[1];
  const void*  mask   = d_in[2];
  const float* hidden = (const float*)d_in[3];
  const float* Wg     = (const float*)d_in[4];
  const float* ag     = (const float*)d_in[5];
  const float* fW     = (const float*)d_in[6];
  const float* fb     = (const float*)d_in[7];
  const float* Wih    = (const float*)d_in[8];
  const float* bih    = (const float*)d_in[9];
  const float* Whh    = (const float*)d_in[10];
  const float* bhh    = (const float*)d_in[11];
  const float* lng    = (const float*)d_in[12];
  const float* lnb    = (const float*)d_in[13];
  const float* W1     = (const float*)d_in[14];
  const float* b1     = (const float*)d_in[15];
  const float* W2     = (const float*)d_in[16];
  const float* b2     = (const float*)d_in[17];
  const float* W3     = (const float*)d_in[18];
  const float* b3     = (const float*)d_in[19];
  char* ws = (char*)d_ws;
  float* out = (float*)d_out;

  int*   flag = (int*)  (ws + OFF_FLAG);
  float* was  = (float*)(ws + OFF_WAS);
  float* wad  = (float*)(ws + OFF_WAD);
  float* wbig = (float*)(ws + OFF_WBIG);
  u16* ffh  = (u16*)(ws + OFF_FFH);   u16* ffl  = (u16*)(ws + OFF_FFL);
  u16* wrzh = (u16*)(ws + OFF_WRZH);  u16* wrzl = (u16*)(ws + OFF_WRZL);
  u16* winh = (u16*)(ws + OFF_WINH);  u16* winl = (u16*)(ws + OFF_WINL);
  u16* whnh = (u16*)(ws + OFF_WHNH);  u16* whnl = (u16*)(ws + OFF_WHNL);
  u16* f1h  = (u16*)(ws + OFF_F1H);   u16* f1l  = (u16*)(ws + OFF_F1L);
  u16* f2h  = (u16*)(ws + OFF_F2H);   u16* f2l  = (u16*)(ws + OFF_F2L);
  u16* xh   = (u16*)(ws + OFF_XCATH); u16* xl   = (u16*)(ws + OFF_XCATL);
  u16* ach  = (u16*)(ws + OFF_ACATH); u16* acl  = (u16*)(ws + OFF_ACATL);
  u16* beh  = (u16*)(ws + OFF_BELH);  u16* bel  = (u16*)(ws + OFF_BELL);
  u16* x1h  = (u16*)(ws + OFF_X1H);   u16* x1l  = (u16*)(ws + OFF_X1L);

  // preprocessing: 2 launches
  k_prep1<<<1937, 256, 0, stream>>>((const unsigned char*)mask, flag, Wg, ag, was, wad,
                                    fW, wbig, Wih, Whh, W1, W2,
                                    wrzh, wrzl, winh, winl, whnh, whnl,
                                    f1h, f1l, f2h, f2l, hidden, ach, acl);
  k_prep2<<<84, 256, 0, stream>>>(wbig, ffh, ffl);

  // GAT -> x_cat (hi/lo)
  k_gat<<<8192, 256, 0, stream>>>(nbr, node, mask, flag, was, wad, xh, xl);

  // fused = relu(x_cat @ Wbig + fb) -> ACAT cols 0..255 (stride 512)
  k_gemm3<21,16,2,4><<<dim3(128,2), 256, 0, stream>>>(xh, xl, KFUSE, ffh, ffl, fb, ach, acl, 512, 0);
  // GRU + LN fused (reads ACAT = [fs|h])
  k_gru<<<256, 512, 0, stream>>>(ach, acl, wrzh, wrzl, winh, winl, whnh, whnl,
                                 bih, bhh, hidden, lng, lnb, out + ACT_TOT, beh, bel);
  // x1 = relu(bel @ W1 + b1)
  k_gemm3<8,16,2,4><<<dim3(128,2), 256, 0, stream>>>(beh, bel, 256, f1h, f1l, b1, x1h, x1l, 256, 0);
  // x2 = relu(x1 @ W2 + b2) in LDS + head + project
  k_w2head<<<128, 256, 0, stream>>>(x1h, x1l, f2h, f2l, b2, W3, b3, out);
}

// Round 7
// 192.093 us; speedup vs baseline: 1.2505x; 1.2505x over previous
//
#include <hip/hip_runtime.h>
#include <hip/hip_bf16.h>

// ActorNetwork fused pipeline for MI355X — round 7.
// k_gat: v3 load/p1b/softmax + LDS-op-minimal stage3 (b128 nb + uniform b64 alpha,
// shfl sub-combine). k_gemm3: A-prefetch pipeline. k_w2head: 32 rows/block, grid 256.

typedef unsigned short u16;
typedef unsigned int   u32;
typedef __attribute__((ext_vector_type(8))) short bf16x8;
typedef __attribute__((ext_vector_type(4))) float f32x4;

#define KFUSE  672   // 641 padded to 21*32
#define ACT_TOT (8192*16)

__device__ __forceinline__ u16 f2bf(float x){
  u32 u = __float_as_uint(x);
  u += 0x7fffu + ((u >> 16) & 1u);   // round-to-nearest-even
  return (u16)(u >> 16);
}
__device__ __forceinline__ float bf2f(u16 h){ return __uint_as_float(((u32)h) << 16); }

// generic: one MFMA B-fragment (64 lanes) from fp32 src
__device__ __forceinline__ void frag_one(const float* __restrict__ src, int ld, int col0,
                                         int NT, u16* __restrict__ dhi, u16* __restrict__ dlo,
                                         int f, int fsrc, int l){
  int kt = fsrc / NT, nt = fsrc % NT;
  int kbase = kt*32 + (l >> 4)*8, n = col0 + nt*16 + (l & 15);
  size_t o = ((size_t)f*64 + l)*8;
  #pragma unroll
  for(int i = 0; i < 8; ++i){
    float w = src[(size_t)(kbase + i)*ld + n];
    u16 h = f2bf(w);
    dhi[o + i] = h;
    dlo[o + i] = f2bf(w - bf2f(h));
  }
}

// ---------- prep kernel 1: probe + wa + wbig + direct weight frags + h split ----------
#define B_WBIG0 1
#define B_WRZA  673
#define B_WRZB  737
#define B_WIN   801
#define B_WHN   833
#define B_F1    865
#define B_F2    897
#define B_SPLIT 913
// grid = 1937
__global__ __launch_bounds__(256) void k_prep1(
    const unsigned char* __restrict__ maskb, int* __restrict__ flag,
    const float* __restrict__ Wg, const float* __restrict__ ag,
    float* __restrict__ was, float* __restrict__ wad,
    const float* __restrict__ fW, float* __restrict__ wbig,
    const float* __restrict__ Wih, const float* __restrict__ Whh,
    const float* __restrict__ W1, const float* __restrict__ W2,
    u16* __restrict__ wrzh, u16* __restrict__ wrzl,
    u16* __restrict__ winh, u16* __restrict__ winl,
    u16* __restrict__ whnh, u16* __restrict__ whnl,
    u16* __restrict__ f1h, u16* __restrict__ f1l,
    u16* __restrict__ f2h, u16* __restrict__ f2l,
    const float* __restrict__ hidden, u16* __restrict__ acath, u16* __restrict__ acatl)
{
  int bx = blockIdx.x, t = threadIdx.x;
  if(bx == 0){
    if(t == 0){
      int s = 0;
      for(int i = 1; i < 256; i += 4) s += maskb[i];
      *flag = (s == 0) ? 1 : 0;
    }
    #pragma unroll
    for(int v = 0; v < 2; ++v){
      int idx = v*256 + t, k = idx & 127, h = idx >> 7;
      float s = 0.f, d = 0.f;
      for(int f = 0; f < 64; ++f){
        float w = Wg[k*256 + h*64 + f];
        s += w * ag[h*128 + f];
        d += w * ag[h*128 + 64 + f];
      }
      was[k*4 + h] = s; wad[k*4 + h] = d;
    }
  } else if(bx < B_WRZA){
    int r = bx - B_WBIG0, j = t;
    float v;
    if(r < 129) v = fW[r*256 + j];
    else if(r < 641){
      int h = (r - 129) >> 7, kk = (r - 129) & 127;
      float s = 0.f;
      for(int f = 0; f < 64; ++f) s += Wg[kk*256 + h*64 + f] * fW[(129 + h*64 + f)*256 + j];
      v = s;
    } else v = 0.f;
    wbig[r*256 + j] = v;
  } else if(bx < B_SPLIT){
    int sub = t >> 6, l = t & 63;
    if(bx < B_WRZB){        // Wih rz: frags 0..255, NT=32
      int f = (bx - B_WRZA)*4 + sub;
      frag_one(Wih, 768, 0, 32, wrzh, wrzl, f, f, l);
    } else if(bx < B_WIN){  // Whh rz: frags 256..511 (src frag 0..255)
      int fl = (bx - B_WRZB)*4 + sub;
      frag_one(Whh, 768, 0, 32, wrzh, wrzl, 256 + fl, fl, l);
    } else if(bx < B_WHN){  // Wih n: 128 frags NT=16 col0 512
      int f = (bx - B_WIN)*4 + sub;
      frag_one(Wih, 768, 512, 16, winh, winl, f, f, l);
    } else if(bx < B_F1){   // Whh n
      int f = (bx - B_WHN)*4 + sub;
      frag_one(Whh, 768, 512, 16, whnh, whnl, f, f, l);
    } else if(bx < B_F2){   // W1: 128 frags NT=16
      int f = (bx - B_F1)*4 + sub;
      frag_one(W1, 256, 0, 16, f1h, f1l, f, f, l);
    } else {                // W2: 64 frags NT=8
      int f = (bx - B_F2)*4 + sub;
      frag_one(W2, 128, 0, 8, f2h, f2l, f, f, l);
    }
  } else {
    // h split -> ACAT cols 256..511 (row stride 512)
    int i = (bx - B_SPLIT)*256 + t;     // 0..262143, 8 f32 each
    int idx8 = i*8, row = idx8 >> 8, col = idx8 & 255;
    const float4* p = (const float4*)(hidden + (size_t)idx8);
    float4 v0 = p[0], v1 = p[1];
    float vv[8] = {v0.x,v0.y,v0.z,v0.w,v1.x,v1.y,v1.z,v1.w};
    u16 h8[8], l8[8];
    #pragma unroll
    for(int q = 0; q < 8; ++q){ u16 h = f2bf(vv[q]); h8[q] = h; l8[q] = f2bf(vv[q] - bf2f(h)); }
    uint4 uh = { (u32)h8[0] | ((u32)h8[1]<<16), (u32)h8[2] | ((u32)h8[3]<<16),
                 (u32)h8[4] | ((u32)h8[5]<<16), (u32)h8[6] | ((u32)h8[7]<<16) };
    uint4 ul = { (u32)l8[0] | ((u32)l8[1]<<16), (u32)l8[2] | ((u32)l8[3]<<16),
                 (u32)l8[4] | ((u32)l8[5]<<16), (u32)l8[6] | ((u32)l8[7]<<16) };
    size_t off = (size_t)row*512 + 256 + col;
    *(uint4*)(acath + off) = uh;
    *(uint4*)(acatl + off) = ul;
  }
}

// ---------- prep kernel 2: wbig frags (depends on prep1) ----------
__global__ __launch_bounds__(256) void k_prep2(
    const float* __restrict__ wbig, u16* __restrict__ ffh, u16* __restrict__ ffl)
{
  int f = blockIdx.x*4 + (threadIdx.x >> 6), l = threadIdx.x & 63;   // 84 blocks -> 336 frags
  frag_one(wbig, 256, 0, 16, ffh, ffl, f, f, l);
}

// ---------- GAT kernel v7: coalesced load, LDS-op-minimal stage 3 ----------
__global__ __launch_bounds__(256) void k_gat(
    const float* __restrict__ nbg, const float* __restrict__ node,
    const void* __restrict__ maskp, const int* __restrict__ flagp,
    const float* __restrict__ was, const float* __restrict__ wad,
    u16* __restrict__ xhi, u16* __restrict__ xlo)
{
  __shared__ float s_nb[8192];     // [n][ch^(n&31)] float4 chunks
  __shared__ float s_wad[512];
  __shared__ float s_ep[1024];     // p1b partials [c][n][4h]; reused: stage3 partials [w][c2][8]
  __shared__ float s_alpha[256];   // [n][4h]
  int b = blockIdx.x, t = threadIdx.x;
  const float* nb = nbg + (size_t)b*8192;
  const int isint = *flagp;

  s_wad[t] = wad[t]; s_wad[t+256] = wad[t+256];

  #pragma unroll
  for(int q = 0; q < 8; ++q){
    int f = q*256 + t;
    int n = f >> 5, ch = f & 31;
    float4 v = *(const float4*)(nb + f*4);
    *(float4*)(s_nb + (n*32 + (ch ^ (n & 31)))*4) = v;
  }

  if(t < 129){
    float v;
    if(t < 2){
      float ph = node[(size_t)b*128] * (6.2831853071795864769f / 24.0f);
      v = (t == 0) ? sinf(ph) : cosf(ph);
    } else v = node[(size_t)b*128 + (t-1)];
    u16 h = f2bf(v);
    size_t o = (size_t)b*KFUSE + t;
    xhi[o] = h; xlo[o] = f2bf(v - bf2f(h));
  } else if(t < 160){
    size_t o = (size_t)b*KFUSE + 641 + (t - 129);
    xhi[o] = 0; xlo[o] = 0;
  }
  __syncthreads();

  // p1b: ed partials from LDS. thread (n = t&63, c = t>>6) handles k-quarter c.
  {
    int n = t & 63, c = t >> 6;
    float adx = 0.f, ady = 0.f, adz = 0.f, adw = 0.f;
    #pragma unroll
    for(int q = 0; q < 8; ++q){
      int ch = c*8 + q;
      float4 v = *(const float4*)(s_nb + (n*32 + (ch ^ (n & 31)))*4);
      float vv[4] = {v.x, v.y, v.z, v.w};
      #pragma unroll
      for(int i2 = 0; i2 < 4; ++i2){
        int k = ch*4 + i2;
        float4 wd = *(const float4*)(s_wad + k*4);
        adx += vv[i2]*wd.x; ady += vv[i2]*wd.y; adz += vv[i2]*wd.z; adw += vv[i2]*wd.w;
      }
    }
    float4 ad = {adx, ady, adz, adw};
    *(float4*)(s_ep + (c*64 + n)*4) = ad;
  }
  __syncthreads();

  // softmax: wave = head h2, lane = neighbor n2; writes alpha [n][4h]
  {
    int n2 = t & 63, h2 = t >> 6;
    float es = 0.f;
    #pragma unroll
    for(int ii = 0; ii < 2; ++ii){
      int k = n2*2 + ii;
      float v0 = s_nb[(k >> 2)*4 + (k & 3)];
      es += v0 * was[k*4 + h2];
    }
    for(int off = 32; off; off >>= 1) es += __shfl_xor(es, off);
    float ed = s_ep[n2*4 + h2] + s_ep[(64+n2)*4 + h2]
             + s_ep[(128+n2)*4 + h2] + s_ep[(192+n2)*4 + h2];
    float e = es + ed;
    e = (e > 0.f) ? e : 0.2f*e;
    bool valid;
    if(isint) valid = ((const u32*)maskp)[(size_t)b*64 + n2] != 0u;
    else      valid = ((const unsigned char*)maskp)[(size_t)b*64 + n2] != 0;
    float ev = valid ? e : -1e30f;
    float m = ev;
    for(int off = 32; off; off >>= 1) m = fmaxf(m, __shfl_xor(m, off));
    float p = valid ? expf(ev - m) : 0.f;
    float s = p;
    for(int off = 32; off; off >>= 1) s += __shfl_xor(s, off);
    s_alpha[n2*4 + h2] = p / s;   // [n][4h]
  }
  __syncthreads();

  // stage 3 v7: thread = (c2 = t&31, sub = bit5, hp = bit6, half = bit7)
  // heads {2hp, 2hp+1}; 16 n's; b128 nb + uniform b64 alpha; shfl_xor(32) sums subs.
  {
    int c2 = t & 31, hp = (t >> 6) & 1, half = t >> 7;
    int sub = (t >> 5) & 1;
    float4 a0 = {0.f,0.f,0.f,0.f}, a1 = {0.f,0.f,0.f,0.f};
    int nbase = half*32 + sub*16;
    #pragma unroll
    for(int i = 0; i < 16; ++i){
      int n = nbase + i;
      float4 v = *(const float4*)(s_nb + (n*32 + (c2 ^ (n & 31)))*4);
      float2 ap = *(const float2*)(s_alpha + n*4 + hp*2);
      a0.x += ap.x*v.x; a0.y += ap.x*v.y; a0.z += ap.x*v.z; a0.w += ap.x*v.w;
      a1.x += ap.y*v.x; a1.y += ap.y*v.y; a1.z += ap.y*v.z; a1.w += ap.y*v.w;
    }
    a0.x += __shfl_xor(a0.x, 32); a0.y += __shfl_xor(a0.y, 32);
    a0.z += __shfl_xor(a0.z, 32); a0.w += __shfl_xor(a0.w, 32);
    a1.x += __shfl_xor(a1.x, 32); a1.y += __shfl_xor(a1.y, 32);
    a1.z += __shfl_xor(a1.z, 32); a1.w += __shfl_xor(a1.w, 32);
    __syncthreads();   // p1b s_ep fully consumed; safe to overwrite
    if((t & 63) < 32){
      int w = t >> 6;   // w = (half<<1)|hp
      *(float4*)(s_ep + (w*32 + c2)*8 + 0) = a0;
      *(float4*)(s_ep + (w*32 + c2)*8 + 4) = a1;
    }
  }
  __syncthreads();
  // final: thread (h = t>>5, cc = t&31) combines halves, writes hi/lo
  if(t < 128){
    int h = t >> 5, cc = t & 31;
    int hp2 = h >> 1, slot = h & 1;
    float4 p0 = *(const float4*)(s_ep + ((0*2 + hp2)*32 + cc)*8 + slot*4);
    float4 p1 = *(const float4*)(s_ep + ((1*2 + hp2)*32 + cc)*8 + slot*4);
    float vv[4] = {p0.x+p1.x, p0.y+p1.y, p0.z+p1.z, p0.w+p1.w};
    size_t o = (size_t)b*KFUSE + 129 + h*128 + cc*4;
    #pragma unroll
    for(int i = 0; i < 4; ++i){
      u16 hh = f2bf(vv[i]);
      xhi[o+i] = hh; xlo[o+i] = f2bf(vv[i] - bf2f(hh));
    }
  }
}

// ---------- split-bf16 MFMA GEMM: ROWF row-frags, col-split, A-prefetch ----------
template<int KT, int NT_TOT, int NPW, int ROWF>
__global__ __launch_bounds__(256) void k_gemm3(
    const u16* __restrict__ xhi, const u16* __restrict__ xlo, int lda,
    const u16* __restrict__ wfhi, const u16* __restrict__ wflo,
    const float* __restrict__ bias,
    u16* __restrict__ ohi, u16* __restrict__ olo, int ost, int ocol)
{
  int l = threadIdx.x & 63, w = threadIdx.x >> 6;
  int m0 = blockIdx.x * (16*ROWF);
  int ntbase = blockIdx.y * (4*NPW) + w*NPW;
  f32x4 acc[NPW][ROWF];
  #pragma unroll
  for(int j = 0; j < NPW; ++j)
    #pragma unroll
    for(int rf = 0; rf < ROWF; ++rf) acc[j][rf] = (f32x4){0.f,0.f,0.f,0.f};
  size_t arow[ROWF];
  #pragma unroll
  for(int rf = 0; rf < ROWF; ++rf)
    arow[rf] = (size_t)(m0 + rf*16 + (l & 15))*lda + (size_t)((l >> 4)*8);
  bf16x8 ah[ROWF], al[ROWF];
  #pragma unroll
  for(int rf = 0; rf < ROWF; ++rf){
    ah[rf] = *(const bf16x8*)(xhi + arow[rf]);
    al[rf] = *(const bf16x8*)(xlo + arow[rf]);
  }
  for(int kt = 0; kt < KT; ++kt){
    bf16x8 ahn[ROWF], aln[ROWF];
    if(kt + 1 < KT){
      #pragma unroll
      for(int rf = 0; rf < ROWF; ++rf){
        ahn[rf] = *(const bf16x8*)(xhi + arow[rf] + (kt+1)*32);
        aln[rf] = *(const bf16x8*)(xlo + arow[rf] + (kt+1)*32);
      }
    }
    #pragma unroll
    for(int j = 0; j < NPW; ++j){
      size_t bo = ((size_t)(kt*NT_TOT + ntbase + j)*64 + l)*8;
      bf16x8 bh = *(const bf16x8*)(wfhi + bo);
      bf16x8 bl = *(const bf16x8*)(wflo + bo);
      #pragma unroll
      for(int rf = 0; rf < ROWF; ++rf){
        acc[j][rf] = __builtin_amdgcn_mfma_f32_16x16x32_bf16(ah[rf], bh, acc[j][rf], 0, 0, 0);
        acc[j][rf] = __builtin_amdgcn_mfma_f32_16x16x32_bf16(ah[rf], bl, acc[j][rf], 0, 0, 0);
        acc[j][rf] = __builtin_amdgcn_mfma_f32_16x16x32_bf16(al[rf], bh, acc[j][rf], 0, 0, 0);
      }
    }
    #pragma unroll
    for(int rf = 0; rf < ROWF; ++rf){ ah[rf] = ahn[rf]; al[rf] = aln[rf]; }
  }
  #pragma unroll
  for(int j = 0; j < NPW; ++j){
    int col = (ntbase + j)*16 + (l & 15);
    float bv = bias[col];
    #pragma unroll
    for(int rf = 0; rf < ROWF; ++rf){
      int r0 = m0 + rf*16 + (l >> 4)*4;
      #pragma unroll
      for(int q = 0; q < 4; ++q){
        float y = fmaxf(acc[j][rf][q] + bv, 0.f);
        size_t o = (size_t)(r0 + q)*ost + ocol + col;
        u16 h = f2bf(y);
        ohi[o] = h; olo[o] = f2bf(y - bf2f(h));
      }
    }
  }
}

// ---------- fused GRU v2: 512 threads, 32 rows/block, 8 waves x 32 cols ----------
__global__ __launch_bounds__(512) void k_gru(
    const u16* __restrict__ ah_, const u16* __restrict__ al_,
    const u16* __restrict__ wrzh, const u16* __restrict__ wrzl,
    const u16* __restrict__ winh, const u16* __restrict__ winl,
    const u16* __restrict__ whnh, const u16* __restrict__ whnl,
    const float* __restrict__ bih, const float* __restrict__ bhh,
    const float* __restrict__ hidden, const float* __restrict__ lng,
    const float* __restrict__ lnb,
    float* __restrict__ hout, u16* __restrict__ belh, u16* __restrict__ bell)
{
  __shared__ float s_s1[256], s_s2[256];
  __shared__ float s_mu[32], s_rs[32];
  int l = threadIdx.x & 63, w = threadIdx.x >> 6;   // 8 waves
  int m0 = blockIdx.x*32;
  f32x4 ar[2][2], az[2][2], aa[2][2], ab[2][2];
  #pragma unroll
  for(int j = 0; j < 2; ++j)
    #pragma unroll
    for(int rf = 0; rf < 2; ++rf){
      ar[j][rf] = (f32x4){0.f,0.f,0.f,0.f}; az[j][rf] = (f32x4){0.f,0.f,0.f,0.f};
      aa[j][rf] = (f32x4){0.f,0.f,0.f,0.f}; ab[j][rf] = (f32x4){0.f,0.f,0.f,0.f};
    }
  size_t arow[2];
  #pragma unroll
  for(int rf = 0; rf < 2; ++rf)
    arow[rf] = (size_t)(m0 + rf*16 + (l & 15))*512 + (size_t)((l >> 4)*8);
  for(int kt = 0; kt < 16; ++kt){
    bf16x8 ah[2], al[2];
    #pragma unroll
    for(int rf = 0; rf < 2; ++rf){
      ah[rf] = *(const bf16x8*)(ah_ + arow[rf] + kt*32);
      al[rf] = *(const bf16x8*)(al_ + arow[rf] + kt*32);
    }
    #pragma unroll
    for(int j = 0; j < 2; ++j){
      int nt = w*2 + j;
      int fr = kt*32 + nt;
      size_t bo = ((size_t)fr*64 + l)*8;
      bf16x8 bh = *(const bf16x8*)(wrzh + bo);
      bf16x8 bl = *(const bf16x8*)(wrzl + bo);
      size_t bo2 = bo + (size_t)16*64*8;    // z-frags at nt+16
      bf16x8 bh2 = *(const bf16x8*)(wrzh + bo2);
      bf16x8 bl2 = *(const bf16x8*)(wrzl + bo2);
      #pragma unroll
      for(int rf = 0; rf < 2; ++rf){
        ar[j][rf] = __builtin_amdgcn_mfma_f32_16x16x32_bf16(ah[rf], bh, ar[j][rf], 0, 0, 0);
        ar[j][rf] = __builtin_amdgcn_mfma_f32_16x16x32_bf16(ah[rf], bl, ar[j][rf], 0, 0, 0);
        ar[j][rf] = __builtin_amdgcn_mfma_f32_16x16x32_bf16(al[rf], bh, ar[j][rf], 0, 0, 0);
        az[j][rf] = __builtin_amdgcn_mfma_f32_16x16x32_bf16(ah[rf], bh2, az[j][rf], 0, 0, 0);
        az[j][rf] = __builtin_amdgcn_mfma_f32_16x16x32_bf16(ah[rf], bl2, az[j][rf], 0, 0, 0);
        az[j][rf] = __builtin_amdgcn_mfma_f32_16x16x32_bf16(al[rf], bh2, az[j][rf], 0, 0, 0);
      }
    }
  }
  for(int kt = 0; kt < 8; ++kt){
    bf16x8 fh[2], fl2[2], gh[2], gl[2];
    #pragma unroll
    for(int rf = 0; rf < 2; ++rf){
      fh[rf]  = *(const bf16x8*)(ah_ + arow[rf] + kt*32);
      fl2[rf] = *(const bf16x8*)(al_ + arow[rf] + kt*32);
      gh[rf]  = *(const bf16x8*)(ah_ + arow[rf] + 256 + kt*32);
      gl[rf]  = *(const bf16x8*)(al_ + arow[rf] + 256 + kt*32);
    }
    #pragma unroll
    for(int j = 0; j < 2; ++j){
      int nt = w*2 + j;
      size_t bo = ((size_t)(kt*16 + nt)*64 + l)*8;
      bf16x8 bh = *(const bf16x8*)(winh + bo);
      bf16x8 bl = *(const bf16x8*)(winl + bo);
      bf16x8 ch = *(const bf16x8*)(whnh + bo);
      bf16x8 cl2 = *(const bf16x8*)(whnl + bo);
      #pragma unroll
      for(int rf = 0; rf < 2; ++rf){
        aa[j][rf] = __builtin_amdgcn_mfma_f32_16x16x32_bf16(fh[rf], bh, aa[j][rf], 0, 0, 0);
        aa[j][rf] = __builtin_amdgcn_mfma_f32_16x16x32_bf16(fh[rf], bl, aa[j][rf], 0, 0, 0);
        aa[j][rf] = __builtin_amdgcn_mfma_f32_16x16x32_bf16(fl2[rf], bh, aa[j][rf], 0, 0, 0);
        ab[j][rf] = __builtin_amdgcn_mfma_f32_16x16x32_bf16(gh[rf], ch, ab[j][rf], 0, 0, 0);
        ab[j][rf] = __builtin_amdgcn_mfma_f32_16x16x32_bf16(gh[rf], cl2, ab[j][rf], 0, 0, 0);
        ab[j][rf] = __builtin_amdgcn_mfma_f32_16x16x32_bf16(gl[rf], ch, ab[j][rf], 0, 0, 0);
      }
    }
  }
  int cl = l & 15, rq = l >> 4;
  float hnew[2][2][4];
  float s1p[2][4], s2p[2][4];
  #pragma unroll
  for(int rf = 0; rf < 2; ++rf)
    #pragma unroll
    for(int q = 0; q < 4; ++q){ s1p[rf][q] = 0.f; s2p[rf][q] = 0.f; }
  #pragma unroll
  for(int j = 0; j < 2; ++j){
    int col = w*32 + j*16 + cl;
    float br = bih[col] + bhh[col];
    float bz = bih[256+col] + bhh[256+col];
    float bi = bih[512+col];
    float bh2 = bhh[512+col];
    #pragma unroll
    for(int rf = 0; rf < 2; ++rf){
      #pragma unroll
      for(int q = 0; q < 4; ++q){
        int row = m0 + rf*16 + rq*4 + q;
        float rs = ar[j][rf][q] + br;
        float zs = az[j][rf][q] + bz;
        float in_ = aa[j][rf][q] + bi;
        float hn  = ab[j][rf][q] + bh2;
        float h   = hidden[(size_t)row*256 + col];
        float r = 1.f/(1.f + expf(-rs));
        float z = 1.f/(1.f + expf(-zs));
        float nv = tanhf(in_ + r*hn);
        float hv = (1.f - z)*nv + z*h;
        hnew[j][rf][q] = hv;
        hout[(size_t)row*256 + col] = hv;
        s1p[rf][q] += hv; s2p[rf][q] += hv*hv;
      }
    }
  }
  #pragma unroll
  for(int rf = 0; rf < 2; ++rf)
    #pragma unroll
    for(int q = 0; q < 4; ++q){
      float a = s1p[rf][q], b2 = s2p[rf][q];
      for(int off = 1; off < 16; off <<= 1){
        a += __shfl_xor(a, off); b2 += __shfl_xor(b2, off);
      }
      if(cl == 0){
        int rloc = rf*16 + rq*4 + q;
        s_s1[w*32 + rloc] = a; s_s2[w*32 + rloc] = b2;
      }
    }
  __syncthreads();
  if(threadIdx.x < 32){
    int rloc = threadIdx.x;
    float t1 = 0.f, t2 = 0.f;
    #pragma unroll
    for(int ww = 0; ww < 8; ++ww){ t1 += s_s1[ww*32 + rloc]; t2 += s_s2[ww*32 + rloc]; }
    float mu = t1 * (1.f/256.f);
    float var = t2 * (1.f/256.f) - mu*mu;
    s_mu[rloc] = mu; s_rs[rloc] = rsqrtf(var + 1e-5f);
  }
  __syncthreads();
  #pragma unroll
  for(int j = 0; j < 2; ++j){
    int col = w*32 + j*16 + cl;
    float g = lng[col], bb = lnb[col];
    #pragma unroll
    for(int rf = 0; rf < 2; ++rf){
      #pragma unroll
      for(int q = 0; q < 4; ++q){
        int rloc = rf*16 + rq*4 + q;
        float bel = (hnew[j][rf][q] - s_mu[rloc]) * s_rs[rloc] * g + bb;
        u16 hb = f2bf(bel);
        size_t o = (size_t)(m0 + rloc)*256 + col;
        belh[o] = hb; bell[o] = f2bf(bel - bf2f(hb));
      }
    }
  }
}

// ---------- fused W2 GEMM + W3 head + project_power: 32 rows/block, grid 256 ----------
__global__ __launch_bounds__(256) void k_w2head(
    const u16* __restrict__ xhi, const u16* __restrict__ xlo,
    const u16* __restrict__ wfhi, const u16* __restrict__ wflo,
    const float* __restrict__ b2, const float* __restrict__ W3,
    const float* __restrict__ b3, float* __restrict__ act)
{
  __shared__ float sx2[32*128];
  __shared__ float sW3[2048];
  int t = threadIdx.x, l = t & 63, w = t >> 6;
  int m0 = blockIdx.x*32;
  for(int i = t; i < 2048; i += 256) sW3[i] = W3[i];
  f32x4 acc[2][2];
  #pragma unroll
  for(int j = 0; j < 2; ++j)
    #pragma unroll
    for(int rf = 0; rf < 2; ++rf) acc[j][rf] = (f32x4){0.f,0.f,0.f,0.f};
  size_t arow[2];
  #pragma unroll
  for(int rf = 0; rf < 2; ++rf)
    arow[rf] = (size_t)(m0 + rf*16 + (l & 15))*256 + (size_t)((l >> 4)*8);
  for(int kt = 0; kt < 8; ++kt){
    bf16x8 ah[2], al[2];
    #pragma unroll
    for(int rf = 0; rf < 2; ++rf){
      ah[rf] = *(const bf16x8*)(xhi + arow[rf] + kt*32);
      al[rf] = *(const bf16x8*)(xlo + arow[rf] + kt*32);
    }
    #pragma unroll
    for(int j = 0; j < 2; ++j){
      size_t bo = ((size_t)(kt*8 + w*2 + j)*64 + l)*8;
      bf16x8 bh = *(const bf16x8*)(wfhi + bo);
      bf16x8 bl = *(const bf16x8*)(wflo + bo);
      #pragma unroll
      for(int rf = 0; rf < 2; ++rf){
        acc[j][rf] = __builtin_amdgcn_mfma_f32_16x16x32_bf16(ah[rf], bh, acc[j][rf], 0, 0, 0);
        acc[j][rf] = __builtin_amdgcn_mfma_f32_16x16x32_bf16(ah[rf], bl, acc[j][rf], 0, 0, 0);
        acc[j][rf] = __builtin_amdgcn_mfma_f32_16x16x32_bf16(al[rf], bh, acc[j][rf], 0, 0, 0);
      }
    }
  }
  int cl = l & 15, rq = l >> 4;
  #pragma unroll
  for(int j = 0; j < 2; ++j){
    int col = (w*2 + j)*16 + cl;
    float bv = b2[col];
    #pragma unroll
    for(int rf = 0; rf < 2; ++rf){
      #pragma unroll
      for(int q = 0; q < 4; ++q){
        int rloc = rf*16 + rq*4 + q;
        sx2[rloc*128 + col] = fmaxf(acc[j][rf][q] + bv, 0.f);
      }
    }
  }
  __syncthreads();
  int j = t & 15, rl = t >> 4;
  #pragma unroll
  for(int rr = 0; rr < 2; ++rr){
    int rloc = rr*16 + rl;
    const float* xr = sx2 + rloc*128;
    float raw = b3[j];
    #pragma unroll 8
    for(int k4 = 0; k4 < 32; ++k4){
      float4 v = *(const float4*)(xr + k4*4);
      raw += v.x*sW3[(k4*4+0)*16 + j] + v.y*sW3[(k4*4+1)*16 + j]
           + v.z*sW3[(k4*4+2)*16 + j] + v.w*sW3[(k4*4+3)*16 + j];
    }
    float c0 = fminf(fmaxf(raw, 0.f), 0.5f);
    float tot = c0;
    for(int off = 8; off; off >>= 1) tot += __shfl_xor(tot, off);
    float mx = raw;
    for(int off = 8; off; off >>= 1) mx = fmaxf(mx, __shfl_xor(mx, off));
    bool feas = (tot <= 1.0f);
    float lo = 0.f, hi = fmaxf(mx, 0.f);
    for(int it = 0; it < 60; ++it){
      float mid = 0.5f*(lo + hi);
      float s = fminf(fmaxf(raw - mid, 0.f), 0.5f);
      for(int off = 8; off; off >>= 1) s += __shfl_xor(s, off);
      bool over = s > 1.0f;
      lo = over ? mid : lo;
      hi = over ? hi : mid;
    }
    float muv = feas ? 0.f : hi;
    act[(size_t)(m0 + rloc)*16 + j] = fminf(fmaxf(raw - muv, 0.f), 0.5f);
  }
}

// ---------- workspace layout (bytes) ----------
#define OFF_FLAG   0u
#define OFF_WAS    4096u
#define OFF_WAD    8192u
#define OFF_WBIG   12288u        // 672*256*4 = 688128
#define OFF_FFH    700416u       // 336 frags * 1024 = 344064
#define OFF_FFL    1044480u
#define OFF_WRZH   1388544u      // 512 frags * 1024 = 524288
#define OFF_WRZL   1912832u
#define OFF_WINH   2437120u      // 128 frags * 1024 = 131072
#define OFF_WINL   2568192u
#define OFF_WHNH   2699264u
#define OFF_WHNL   2830336u
#define OFF_F1H    2961408u      // 128 frags
#define OFF_F1L    3092480u
#define OFF_F2H    3223552u      // 64 frags * 1024 = 65536
#define OFF_F2L    3289088u
#define OFF_XCATH  3354624u      // 8192*672*2 = 11010048
#define OFF_XCATL  14364672u
#define OFF_ACATH  25374720u     // 8192*512*2 = 8388608
#define OFF_ACATL  33763328u
#define OFF_BELH   42151936u     // 8192*256*2 = 4194304
#define OFF_BELL   46346240u
#define OFF_X1H    50540544u
#define OFF_X1L    54734848u
// total: 58,929,152 bytes

extern "C" void kernel_launch(void* const* d_in, const int* in_sizes, int n_in,
                              void* d_out, int out_size, void* d_ws, size_t ws_size,
                              hipStream_t stream){
  const float* node   = (const float*)d_in[0];
  const float* nbr    = (const float*)d_in[1];
  const void*  mask   = d_in[2];
  const float* hidden = (const float*)d_in[3];
  const float* Wg     = (const float*)d_in[4];
  const float* ag     = (const float*)d_in[5];
  const float* fW     = (const float*)d_in[6];
  const float* fb     = (const float*)d_in[7];
  const float* Wih    = (const float*)d_in[8];
  const float* bih    = (const float*)d_in[9];
  const float* Whh    = (const float*)d_in[10];
  const float* bhh    = (const float*)d_in[11];
  const float* lng    = (const float*)d_in[12];
  const float* lnb    = (const float*)d_in[13];
  const float* W1     = (const float*)d_in[14];
  const float* b1     = (const float*)d_in[15];
  const float* W2     = (const float*)d_in[16];
  const float* b2     = (const float*)d_in[17];
  const float* W3     = (const float*)d_in[18];
  const float* b3     = (const float*)d_in[19];
  char* ws = (char*)d_ws;
  float* out = (float*)d_out;

  int*   flag = (int*)  (ws + OFF_FLAG);
  float* was  = (float*)(ws + OFF_WAS);
  float* wad  = (float*)(ws + OFF_WAD);
  float* wbig = (float*)(ws + OFF_WBIG);
  u16* ffh  = (u16*)(ws + OFF_FFH);   u16* ffl  = (u16*)(ws + OFF_FFL);
  u16* wrzh = (u16*)(ws + OFF_WRZH);  u16* wrzl = (u16*)(ws + OFF_WRZL);
  u16* winh = (u16*)(ws + OFF_WINH);  u16* winl = (u16*)(ws + OFF_WINL);
  u16* whnh = (u16*)(ws + OFF_WHNH);  u16* whnl = (u16*)(ws + OFF_WHNL);
  u16* f1h  = (u16*)(ws + OFF_F1H);   u16* f1l  = (u16*)(ws + OFF_F1L);
  u16* f2h  = (u16*)(ws + OFF_F2H);   u16* f2l  = (u16*)(ws + OFF_F2L);
  u16* xh   = (u16*)(ws + OFF_XCATH); u16* xl   = (u16*)(ws + OFF_XCATL);
  u16* ach  = (u16*)(ws + OFF_ACATH); u16* acl  = (u16*)(ws + OFF_ACATL);
  u16* beh  = (u16*)(ws + OFF_BELH);  u16* bel  = (u16*)(ws + OFF_BELL);
  u16* x1h  = (u16*)(ws + OFF_X1H);   u16* x1l  = (u16*)(ws + OFF_X1L);

  // preprocessing: 2 launches
  k_prep1<<<1937, 256, 0, stream>>>((const unsigned char*)mask, flag, Wg, ag, was, wad,
                                    fW, wbig, Wih, Whh, W1, W2,
                                    wrzh, wrzl, winh, winl, whnh, whnl,
                                    f1h, f1l, f2h, f2l, hidden, ach, acl);
  k_prep2<<<84, 256, 0, stream>>>(wbig, ffh, ffl);

  // GAT -> x_cat (hi/lo)
  k_gat<<<8192, 256, 0, stream>>>(nbr, node, mask, flag, was, wad, xh, xl);

  // fused = relu(x_cat @ Wbig + fb) -> ACAT cols 0..255 (stride 512)
  k_gemm3<21,16,2,4><<<dim3(128,2), 256, 0, stream>>>(xh, xl, KFUSE, ffh, ffl, fb, ach, acl, 512, 0);
  // GRU + LN fused (reads ACAT = [fs|h])
  k_gru<<<256, 512, 0, stream>>>(ach, acl, wrzh, wrzl, winh, winl, whnh, whnl,
                                 bih, bhh, hidden, lng, lnb, out + ACT_TOT, beh, bel);
  // x1 = relu(bel @ W1 + b1)
  k_gemm3<8,16,2,4><<<dim3(128,2), 256, 0, stream>>>(beh, bel, 256, f1h, f1l, b1, x1h, x1l, 256, 0);
  // x2 = relu(x1 @ W2 + b2) in LDS + head + project (32 rows/block)
  k_w2head<<<256, 256, 0, stream>>>(x1h, x1l, f2h, f2l, b2, W3, b3, out);
}